// Round 1
// baseline (104.903 us; speedup 1.0000x reference)
//
#include <hip/hip_runtime.h>

// Backflow: out[b] = sum_d det(g[b,d]) * bf[d], where
//   g[b,d][i][j] = sum_h h2[b,h]*Wg[h,d,sel[b,i],j] + bg[d,sel[b,i],j]
//   sel[b] = indices of first 16 nonzeros of x[b], h2 = 2-layer relu MLP(x).
// B=8192, O=64, E=16, D=16, H=4.
//
// One wave (64 lanes) per sample. 4 groups of 16 lanes; each group does one
// 16x16 determinant per t-iteration (d = grp*4 + t), row-per-lane Gaussian
// elimination with partial pivoting (virtual swaps, sign via vrow tracking).

__global__ __launch_bounds__(256) void backflow_kernel(
    const float* __restrict__ x,    // (B,64)
    const float* __restrict__ W1,   // (64,4)
    const float* __restrict__ b1,   // (4,)
    const float* __restrict__ W2,   // (4,4)
    const float* __restrict__ b2,   // (4,)
    const float* __restrict__ Wg,   // (4,16,64,16)
    const float* __restrict__ bg,   // (16,64,16)
    const float* __restrict__ bf,   // (16,1)
    float* __restrict__ out,        // (B,)
    int B)
{
    const int lane = threadIdx.x & 63;
    const int wave = threadIdx.x >> 6;
    const int b    = blockIdx.x * 4 + wave;
    if (b >= B) return;
    const int r   = lane & 15;   // row within det group
    const int grp = lane >> 4;   // det group 0..3 within wave

    // ---- occupied-orbital mask + per-row selected index ----
    const float xv = x[b * 64 + lane];
    const unsigned long long mask = __ballot(xv != 0.0f);
    unsigned long long m = mask;
    for (int i = 0; i < r; ++i) m &= (m - 1ull);           // clear r lowest set bits
    const int  sel_r = m ? (int)__builtin_ctzll(m) : 0;    // r-th set bit (fill 0)
    const bool empty = ((mask & ~1ull) == 0ull);           // sum(sel)==0 case

    // ---- h1 = relu(x @ W1 + b1): 64-lane butterfly reduce of x_l * W1[l,:] ----
    float c0 = xv * W1[lane * 4 + 0];
    float c1 = xv * W1[lane * 4 + 1];
    float c2 = xv * W1[lane * 4 + 2];
    float c3 = xv * W1[lane * 4 + 3];
    #pragma unroll
    for (int off = 32; off >= 1; off >>= 1) {
        c0 += __shfl_xor(c0, off);
        c1 += __shfl_xor(c1, off);
        c2 += __shfl_xor(c2, off);
        c3 += __shfl_xor(c3, off);
    }
    const float h10 = fmaxf(c0 + b1[0], 0.0f);
    const float h11 = fmaxf(c1 + b1[1], 0.0f);
    const float h12 = fmaxf(c2 + b1[2], 0.0f);
    const float h13 = fmaxf(c3 + b1[3], 0.0f);

    // ---- h2 = relu(h1 @ W2 + b2) (redundant per lane; 16 FMA) ----
    float h2[4];
    #pragma unroll
    for (int j = 0; j < 4; ++j) {
        float v = b2[j];
        v = fmaf(h10, W2[0 * 4 + j], v);
        v = fmaf(h11, W2[1 * 4 + j], v);
        v = fmaf(h12, W2[2 * 4 + j], v);
        v = fmaf(h13, W2[3 * 4 + j], v);
        h2[j] = fmaxf(v, 0.0f);
    }

    float acc = 0.0f;
    #pragma unroll 1   // keep LU code size bounded; 4 sequential d's per group
    for (int t = 0; t < 4; ++t) {
        const int d = grp * 4 + t;

        // ---- build row r of g[b,d]: 16 floats in registers ----
        const float4* wp0 = reinterpret_cast<const float4*>(Wg + (size_t)((0 * 16 + d) * 64 + sel_r) * 16);
        const float4* wp1 = reinterpret_cast<const float4*>(Wg + (size_t)((1 * 16 + d) * 64 + sel_r) * 16);
        const float4* wp2 = reinterpret_cast<const float4*>(Wg + (size_t)((2 * 16 + d) * 64 + sel_r) * 16);
        const float4* wp3 = reinterpret_cast<const float4*>(Wg + (size_t)((3 * 16 + d) * 64 + sel_r) * 16);
        const float4* bgp = reinterpret_cast<const float4*>(bg + (size_t)(d * 64 + sel_r) * 16);

        float row[16];
        #pragma unroll
        for (int q = 0; q < 4; ++q) {
            const float4 a0 = wp0[q], a1 = wp1[q], a2 = wp2[q], a3 = wp3[q], ab = bgp[q];
            row[q * 4 + 0] = fmaf(h2[0], a0.x, fmaf(h2[1], a1.x, fmaf(h2[2], a2.x, fmaf(h2[3], a3.x, ab.x))));
            row[q * 4 + 1] = fmaf(h2[0], a0.y, fmaf(h2[1], a1.y, fmaf(h2[2], a2.y, fmaf(h2[3], a3.y, ab.y))));
            row[q * 4 + 2] = fmaf(h2[0], a0.z, fmaf(h2[1], a1.z, fmaf(h2[2], a2.z, fmaf(h2[3], a3.z, ab.z))));
            row[q * 4 + 3] = fmaf(h2[0], a0.w, fmaf(h2[1], a1.w, fmaf(h2[2], a2.w, fmaf(h2[3], a3.w, ab.w))));
        }

        // ---- LU with partial pivoting, row-per-lane over 16-lane group ----
        double det  = 1.0;
        float  sign = 1.0f;
        int    vrow = r;      // virtual position of this lane's row
        #pragma unroll
        for (int k = 0; k < 16; ++k) {
            const bool  active = (vrow >= k);
            const float av = active ? fabsf(row[k]) : -1.0f;
            float mv = av;
            mv = fmaxf(mv, __shfl_xor(mv, 1, 16));
            mv = fmaxf(mv, __shfl_xor(mv, 2, 16));
            mv = fmaxf(mv, __shfl_xor(mv, 4, 16));
            mv = fmaxf(mv, __shfl_xor(mv, 8, 16));
            const unsigned long long bal = __ballot(active && (av == mv));
            const int p = (int)__builtin_ctzll((bal >> (grp * 16)) & 0xFFFFull);

            const float pivot = __shfl(row[k], p, 16);
            const int   vp    = __shfl(vrow, p, 16);
            sign = (vp != k) ? -sign : sign;
            if (r == p)            vrow = k;
            else if (vrow == k)    vrow = vp;

            det *= (double)pivot;

            const float pinv = (pivot != 0.0f) ? __builtin_amdgcn_rcpf(pivot) : 0.0f;
            const float f    = (vrow > k) ? row[k] * pinv : 0.0f;
            #pragma unroll
            for (int j = k + 1; j < 16; ++j) {
                const float pv = __shfl(row[j], p, 16);
                row[j] = fmaf(-f, pv, row[j]);
            }
        }

        const float detf = sign * (float)det;
        acc = fmaf(detf, bf[d], acc);
    }

    // ---- reduce the 4 groups' partial sums (uniform within each group) ----
    acc += __shfl_xor(acc, 16);
    acc += __shfl_xor(acc, 32);
    if (lane == 0) out[b] = empty ? 0.0f : acc;
}

extern "C" void kernel_launch(void* const* d_in, const int* in_sizes, int n_in,
                              void* d_out, int out_size, void* d_ws, size_t ws_size,
                              hipStream_t stream) {
    const float* x  = (const float*)d_in[0];
    const float* W1 = (const float*)d_in[1];
    const float* b1 = (const float*)d_in[2];
    const float* W2 = (const float*)d_in[3];
    const float* b2 = (const float*)d_in[4];
    const float* Wg = (const float*)d_in[5];
    const float* bg = (const float*)d_in[6];
    const float* bf = (const float*)d_in[7];
    float* out = (float*)d_out;

    const int B = in_sizes[0] / 64;
    const int blocks = (B + 3) / 4;   // 4 samples (waves) per 256-thread block
    backflow_kernel<<<blocks, 256, 0, stream>>>(x, W1, b1, W2, b2, Wg, bg, bf, out, B);
}